// Round 8
// baseline (290.083 us; speedup 1.0000x reference)
//
#include <hip/hip_runtime.h>
#include <math.h>

#define LAMBDA_DAG 0.5f
#define SCAN_U 8
#define TILEN (256 * SCAN_U)   // float4 per block-tile (2048) = 32 KB
#define LBUF_CAP 2048          // per-block LDS edge buffer

typedef float f4v __attribute__((ext_vector_type(4)));

// Inline fallback (only reachable in the non-fused path, where pT is ready).
__device__ __forceinline__ void process_edge_inline(
        unsigned e, const float* __restrict__ pT,
        float* __restrict__ per_term, float* __restrict__ npar, int B, int C) {
    const unsigned ui = e / (unsigned)C;
    const int i = (int)ui;
    const int j = (int)(e - ui * (unsigned)C);
    float s = 0.f;
    for (int b = 0; b < B; ++b) {
        float df = fmaxf(pT[(size_t)i * B + b] - pT[(size_t)j * B + b], 0.f);
        s += df * df;
    }
    atomicAdd(&per_term[i], s);
    atomicAdd(&npar[i], 1.f);
}

// Round-5 A/B verdict: nontemporal loads ~2x faster per byte than cached for
// the streamed-once dag (poison fill leaves L3 dirty; allocating reads force
// victim writebacks). Round-7 lesson: scan rate ~ aggregate in-flight load
// bytes -> keep 2048 scan blocks (halving them cost 1.5x).
__device__ __forceinline__ f4v ld4nt(const float* p) {
    return __builtin_nontemporal_load((const f4v*)p);
}

// push edge into this block's private segment (LDS-staged; direct global
// write past LBUF_CAP; inline only in non-fused overflow).
#define PUSH_EDGE(E)                                                        \
    {                                                                       \
        const int pos = atomicAdd(&lcnt, 1);                                \
        if (pos < LBUF_CAP) lbuf[pos] = (E);                                \
        else if (pos < segw) seg[pos] = (E);                                \
        else if (inline_ok) process_edge_inline((E), pT, per_term, npar,    \
                                                B, C);                      \
    }

#define PROCESS_TILE(R, tbase)                                              \
    {                                                                       \
        unsigned any = 0u;                                                  \
        _Pragma("unroll")                                                   \
        for (int u = 0; u < SCAN_U; ++u)                                    \
            any |= __float_as_uint(R[u][0]) | __float_as_uint(R[u][1]) |    \
                   __float_as_uint(R[u][2]) | __float_as_uint(R[u][3]);     \
        if (any != 0u) {                                                    \
            _Pragma("unroll")                                               \
            for (int u = 0; u < SCAN_U; ++u) {                              \
                _Pragma("unroll")                                           \
                for (int k = 0; k < 4; ++k) {                               \
                    if (R[u][k] > 0.f) {                                    \
                        const unsigned e = (unsigned)(((tbase) + u * 256 +  \
                                           (int)threadIdx.x) * 4 + k);      \
                        PUSH_EDGE(e);                                       \
                    }                                                       \
                }                                                           \
            }                                                               \
        }                                                                   \
    }

// ---- Fused kernel: blocks [0,nbA) = probs/BCE/zeroing; rest = dag scan -----
// Scan writes edges into PRE-PARTITIONED per-block segments (no global
// counter), so the scan has zero dependency on the probs part.
__global__ void __launch_bounds__(256) k_main(
        const float* __restrict__ logits,
        const float* __restrict__ labels,
        const float* __restrict__ dag,
        float* __restrict__ pT,        // [C*B] transposed probs
        float* __restrict__ bce_part,  // [nbA]
        float* __restrict__ per_term,  // [C] zeroed by probs blocks
        float* __restrict__ npar,      // [C] zeroed by probs blocks
        unsigned* __restrict__ elist,  // nseg * segw edge slots
        int* __restrict__ bcount,      // [nseg]
        int* __restrict__ done,        // [1] zeroed by probs block 0
        int segw, int inline_ok,
        int tb, int te,                // tile range for this launch
        int sb_base, int sbN,          // segment base / scan blocks here
        int do_tails,
        int nbAx, int nbAy, int B, int C) {
    const int nbA = nbAx * nbAy;
    const int bid = blockIdx.x;
    const int tid = threadIdx.x;

    __shared__ float tile[64][17];
    __shared__ float sred[256];
    __shared__ unsigned lbuf[LBUF_CAP];
    __shared__ int lcnt;

    if (bid < nbA) {
        // ---------------- probs + BCE + zero accumulators ------------------
        if (bid == 0 && tid == 0) *done = 0;
        for (int i = bid * 256 + tid; i < C; i += nbA * 256) {
            per_term[i] = 0.f;
            npar[i] = 0.f;
        }
        const int bx = bid % nbAx, by = bid / nbAx;
        const int c0 = bx * 64;
        const int b0 = by * 16;
        const int rows = (B - b0 < 16) ? (B - b0) : 16;
        const int lc = tid & 63;
        const int c  = c0 + lc;
        const bool valid = (c < C);
        float acc = 0.f;
        if (rows > 0) {
            for (int r = tid >> 6; r < rows; r += 4) {
                const int b = b0 + r;
                float l = 0.f, y = 0.f;
                if (valid) {
                    l = logits[(size_t)b * C + c];
                    y = labels[(size_t)b * C + c];
                    // logaddexp(0,l) = max(l,0) + log1p(exp(-|l|))
                    acc += fmaxf(l, 0.f) + log1pf(expf(-fabsf(l))) - l * y;
                }
                tile[lc][r] = 1.f / (1.f + expf(-l));
            }
        }
        __syncthreads();
        if (rows > 0) {
            if ((rows & 3) == 0) {
                const int r4 = rows >> 2;
                const int tot = 64 * r4;
                for (int t = tid; t < tot; t += 256) {
                    const int row = t / r4;
                    const int q = t - row * r4;
                    const int c2 = c0 + row;
                    if (c2 < C) {
                        float4 v;
                        v.x = tile[row][q * 4 + 0];
                        v.y = tile[row][q * 4 + 1];
                        v.z = tile[row][q * 4 + 2];
                        v.w = tile[row][q * 4 + 3];
                        *(float4*)(pT + (size_t)c2 * B + b0 + q * 4) = v;
                    }
                }
            } else {
                const int tot = 64 * rows;
                for (int t = tid; t < tot; t += 256) {
                    const int row = t / rows;
                    const int r = t - row * rows;
                    const int c2 = c0 + row;
                    if (c2 < C) pT[(size_t)c2 * B + b0 + r] = tile[row][r];
                }
            }
        }
        sred[tid] = acc;
        __syncthreads();
        for (int s = 128; s > 0; s >>= 1) {
            if (tid < s) sred[tid] += sred[tid + s];
            __syncthreads();
        }
        if (tid == 0) bce_part[bid] = sred[0];
        return;
    }

    // ---------------- dag scan & compact (segmented, all-nt) ---------------
    const int lsb = bid - nbA;          // local scan block index [0, sbN)
    const int sb  = sb_base + lsb;      // global segment index
    if (tid == 0) lcnt = 0;
    __syncthreads();
    unsigned* __restrict__ seg = elist + (size_t)sb * (size_t)segw;

    const int N  = C * C;
    const int N4 = N >> 2;
    const int NT = N4 / TILEN;
    const int span = (te > tb) ? ((te - tb) + sbN - 1) / sbN : 0;
    const int t0 = tb + lsb * span;
    const int t1 = (t0 + span < te) ? (t0 + span) : te;

    if (t0 < t1) {
        const float* p = dag + ((size_t)t0 * TILEN + tid) * 4;
        f4v a[SCAN_U], b[SCAN_U];
#pragma unroll
        for (int u = 0; u < SCAN_U; ++u) a[u] = ld4nt(p + u * 1024);
        for (int t = t0; t < t1; ++t) {
            const bool last = (t + 1 == t1);
            if (!last) {
#pragma unroll
                for (int u = 0; u < SCAN_U; ++u)
                    b[u] = ld4nt(p + TILEN * 4 + u * 1024);
            }
            PROCESS_TILE(a, t * TILEN);
            if (!last) {
#pragma unroll
                for (int u = 0; u < SCAN_U; ++u) a[u] = b[u];
            }
            p += TILEN * 4;
        }
    }

    if (do_tails) {
        // float4 tail (N4 % TILEN)
        for (int q = NT * TILEN + lsb * 256 + tid; q < N4; q += sbN * 256) {
            f4v d = ld4nt(dag + (size_t)q * 4);
#pragma unroll
            for (int k = 0; k < 4; ++k) {
                if (d[k] > 0.f) {
                    const unsigned e = (unsigned)(q * 4 + k);
                    PUSH_EDGE(e);
                }
            }
        }
        // scalar tail (N % 4)
        for (int e = (N4 << 2) + lsb * 256 + tid; e < N; e += sbN * 256) {
            if (dag[e] > 0.f) PUSH_EDGE((unsigned)e);
        }
    }

    __syncthreads();
    const int n  = lcnt;
    const int nl = (n < LBUF_CAP) ? n : LBUF_CAP;
    for (int t = tid; t < nl; t += 256)
        if (t < segw) seg[t] = lbuf[t];
    if (tid == 0) bcount[sb] = (n < segw) ? n : segw;
}

// ---- Edge processing + fused final reduction -------------------------------
// One block per segment, wave per edge, lane = batch index (256B contiguous
// reads of L2-resident pT). Last block to finish does the final scalar
// reduction (saves one launch).
__global__ void __launch_bounds__(256) k_edges(
        const float* __restrict__ pT,
        const unsigned* __restrict__ elist,
        const int* __restrict__ bcount, int segw, int nseg,
        float* __restrict__ per_term,
        float* __restrict__ npar,
        const float* __restrict__ bce_part, int nbA,
        int* __restrict__ done,
        float* __restrict__ out,
        int B, int C) {
    const int lane = threadIdx.x & 63;
    const int w    = threadIdx.x >> 6;  // wave in block, 0..3
    for (int sb = blockIdx.x; sb < nseg; sb += gridDim.x) {
        int n = bcount[sb];
        if (n > segw) n = segw;
        const unsigned* seg = elist + (size_t)sb * (size_t)segw;
        for (int t = w; t < n; t += 4) {
            const unsigned e = seg[t];
            const unsigned ui = e / (unsigned)C;
            const int i = (int)ui;
            const int j = (int)(e - ui * (unsigned)C);
            const float* pi = pT + (size_t)i * B;
            const float* pj = pT + (size_t)j * B;
            float s = 0.f;
            for (int b = lane; b < B; b += 64) {
                float df = fmaxf(pi[b] - pj[b], 0.f);
                s += df * df;
            }
#pragma unroll
            for (int off = 32; off > 0; off >>= 1) s += __shfl_down(s, off, 64);
            if (lane == 0) {
                atomicAdd(&per_term[i], s);
                atomicAdd(&npar[i], 1.f);
            }
        }
    }

    // ---- last-block-done final reduction ----
    __shared__ bool last;
    __threadfence();
    __syncthreads();
    if (threadIdx.x == 0)
        last = (atomicAdd(done, 1) == (int)gridDim.x - 1);
    __syncthreads();
    if (!last) return;

    float bs = 0.f, ps = 0.f, es = 0.f;
    for (int k = threadIdx.x; k < nbA; k += blockDim.x) bs += bce_part[k];
    for (int i = threadIdx.x; i < C; i += blockDim.x) {
        float np = npar[i];
        es += np;
        if (np > 0.f) ps += per_term[i] / ((float)B * np);
    }
    __shared__ float s1[256], s2[256], s3[256];
    s1[threadIdx.x] = bs;
    s2[threadIdx.x] = ps;
    s3[threadIdx.x] = es;
    __syncthreads();
    for (int s = 128; s > 0; s >>= 1) {
        if (threadIdx.x < s) {
            s1[threadIdx.x] += s1[threadIdx.x + s];
            s2[threadIdx.x] += s2[threadIdx.x + s];
            s3[threadIdx.x] += s3[threadIdx.x + s];
        }
        __syncthreads();
    }
    if (threadIdx.x == 0) {
        float penalty = (s3[0] > 0.f) ? (s2[0] / s3[0]) : 0.f;
        out[0] = s1[0] / (float)(B * C) + LAMBDA_DAG * penalty;
    }
}

extern "C" void kernel_launch(void* const* d_in, const int* in_sizes, int n_in,
                              void* d_out, int out_size, void* d_ws, size_t ws_size,
                              hipStream_t stream) {
    const float* logits = (const float*)d_in[0];
    const float* labels = (const float*)d_in[1];
    const float* dag    = (const float*)d_in[2];
    float* out = (float*)d_out;

    const int C = (int)(sqrt((double)in_sizes[2]) + 0.5);
    const int B = in_sizes[0] / C;

    const int gridAx = (C + 63) / 64;
    const int gridAy = (B + 15) / 16;
    const int nbA = gridAx * gridAy;

    const int N4 = (C * C) >> 2;
    const int NT = N4 / TILEN;                     // 3051 full tiles at C=5000
    const int scanB = 2048;                        // R6-proven parallelism
    const int nseg = scanB;
    const int span = (NT > 0) ? (NT + scanB - 1) / scanB : 0;
    const long long segw_full = (long long)(span + 1) * TILEN * 4;

    float* ws       = (float*)d_ws;
    float* pT       = ws;                          // C*B
    float* per_term = pT + (size_t)C * B;          // C
    float* nparw    = per_term + C;                // C
    float* bce_part = nparw + C;                   // nbA
    int*   bcount   = (int*)(bce_part + nbA);      // nseg
    int*   done     = bcount + nseg;               // 1
    unsigned* elist = (unsigned*)(done + 1);       // nseg * segw

    const size_t base_words = (size_t)C * B + 2 * (size_t)C + nbA + nseg + 1;
    const size_t ws_words = ws_size / 4;
    long long avail = (ws_words > base_words)
                    ? (long long)(ws_words - base_words) : 0;

    int fused, inline_ok, segw;
    if (avail >= segw_full * nseg) {
        fused = 1; inline_ok = 0;
        segw = (int)segw_full;
    } else {
        fused = 0; inline_ok = 1;                  // probs first, inline overflow
        long long sw = avail / nseg;
        if (sw > 0x7fffffffLL) sw = 0x7fffffffLL;
        segw = (int)(sw < 0 ? 0 : sw);
    }

    if (fused) {
        // Single fused launch: probs blocks + all-nt scan of every tile + tails
        k_main<<<nbA + scanB, 256, 0, stream>>>(
            logits, labels, dag, pT, bce_part, per_term, nparw,
            elist, bcount, done, segw, 0,
            0, NT, 0, scanB, 1, gridAx, gridAy, B, C);
    } else {
        k_main<<<nbA, 256, 0, stream>>>(           // probs only (zeroes done)
            logits, labels, dag, pT, bce_part, per_term, nparw,
            elist, bcount, done, segw, 0,
            0, 0, 0, 1, 0, gridAx, gridAy, B, C);
        k_main<<<scanB, 256, 0, stream>>>(         // scan with inline overflow
            logits, labels, dag, pT, bce_part, per_term, nparw,
            elist, bcount, done, segw, inline_ok,
            0, NT, 0, scanB, 1, 0, 0, B, C);
    }

    k_edges<<<nseg, 256, 0, stream>>>(pT, elist, bcount, segw, nseg,
                                      per_term, nparw, bce_part, nbA,
                                      done, out, B, C);
}

// Round 9
// 167.299 us; speedup vs baseline: 1.7339x; 1.7339x over previous
//
#include <hip/hip_runtime.h>
#include <math.h>

#define LAMBDA_DAG 0.5f
#define SCAN_U 8
#define TILEN (256 * SCAN_U)   // float4 per block-tile (2048) = 32 KB
#define LBUF_CAP 2048          // per-block LDS edge buffer

typedef float f4v __attribute__((ext_vector_type(4)));

// Inline fallback (only reachable in the non-fused path, where pT is ready).
__device__ __forceinline__ void process_edge_inline(
        unsigned e, const float* __restrict__ pT,
        float* __restrict__ per_term, float* __restrict__ npar, int B, int C) {
    const unsigned ui = e / (unsigned)C;
    const int i = (int)ui;
    const int j = (int)(e - ui * (unsigned)C);
    float s = 0.f;
    for (int b = 0; b < B; ++b) {
        float df = fmaxf(pT[(size_t)i * B + b] - pT[(size_t)j * B + b], 0.f);
        s += df * df;
    }
    atomicAdd(&per_term[i], s);
    atomicAdd(&npar[i], 1.f);
}

// Round-5 A/B verdict: nontemporal loads ran ~2x faster per byte than cached
// (the poison fill leaves L3 full of dirty lines; allocating reads force
// victim writebacks). dag has zero reuse -> nt is semantically ideal.
// Round-7 lesson: scan rate tracks aggregate in-flight load bytes -> 2048
// scan blocks (halving them cost 1.5x).
// Round-8 lesson: NO single-line device atomics / threadfence fan-in (2048
// same-line RMWs serialized at ~72ns each = 147us). Keep k_final separate.
__device__ __forceinline__ f4v ld4nt(const float* p) {
    return __builtin_nontemporal_load((const f4v*)p);
}

// push edge into this block's private segment (LDS-staged)
#define PUSH_EDGE(E)                                                        \
    {                                                                       \
        const int pos = atomicAdd(&lcnt, 1);                                \
        if (pos < LBUF_CAP) lbuf[pos] = (E);                                \
        else if (pos < segw) seg[pos] = (E);                                \
        else if (inline_ok) process_edge_inline((E), pT, per_term, npar,    \
                                                B, C);                      \
    }

#define PROCESS_TILE(R, tbase)                                              \
    {                                                                       \
        unsigned any = 0u;                                                  \
        _Pragma("unroll")                                                   \
        for (int u = 0; u < SCAN_U; ++u)                                    \
            any |= __float_as_uint(R[u][0]) | __float_as_uint(R[u][1]) |    \
                   __float_as_uint(R[u][2]) | __float_as_uint(R[u][3]);     \
        if (any != 0u) {                                                    \
            _Pragma("unroll")                                               \
            for (int u = 0; u < SCAN_U; ++u) {                              \
                _Pragma("unroll")                                           \
                for (int k = 0; k < 4; ++k) {                               \
                    if (R[u][k] > 0.f) {                                    \
                        const unsigned e = (unsigned)(((tbase) + u * 256 +  \
                                           (int)threadIdx.x) * 4 + k);      \
                        PUSH_EDGE(e);                                       \
                    }                                                       \
                }                                                           \
            }                                                               \
        }                                                                   \
    }

// ---- Fused kernel: blocks [0,nbA) = probs/BCE/zeroing; rest = dag scan -----
// Scan writes edges into PRE-PARTITIONED per-block segments (no global
// counter), so the scan has zero dependency on the probs part.
__global__ void __launch_bounds__(256) k_main(
        const float* __restrict__ logits,
        const float* __restrict__ labels,
        const float* __restrict__ dag,
        float* __restrict__ pT,        // [C*B] transposed probs
        float* __restrict__ bce_part,  // [nbA]
        float* __restrict__ per_term,  // [C] zeroed by probs blocks
        float* __restrict__ npar,      // [C] zeroed by probs blocks
        unsigned* __restrict__ elist,  // nseg * segw edge slots
        int* __restrict__ bcount,      // [nseg]
        int segw, int inline_ok,
        int tb, int te,                // tile range for this launch
        int sb_base, int sbN,          // segment base / scan blocks here
        int do_tails,
        int nbAx, int nbAy, int B, int C) {
    const int nbA = nbAx * nbAy;
    const int bid = blockIdx.x;
    const int tid = threadIdx.x;

    __shared__ float tile[64][17];
    __shared__ float sred[256];
    __shared__ unsigned lbuf[LBUF_CAP];
    __shared__ int lcnt;

    if (bid < nbA) {
        // ---------------- probs + BCE + zero accumulators ------------------
        for (int i = bid * 256 + tid; i < C; i += nbA * 256) {
            per_term[i] = 0.f;
            npar[i] = 0.f;
        }
        const int bx = bid % nbAx, by = bid / nbAx;
        const int c0 = bx * 64;
        const int b0 = by * 16;
        const int rows = (B - b0 < 16) ? (B - b0) : 16;
        const int lc = tid & 63;
        const int c  = c0 + lc;
        const bool valid = (c < C);
        float acc = 0.f;
        if (rows > 0) {
            for (int r = tid >> 6; r < rows; r += 4) {
                const int b = b0 + r;
                float l = 0.f, y = 0.f;
                if (valid) {
                    l = logits[(size_t)b * C + c];
                    y = labels[(size_t)b * C + c];
                    // logaddexp(0,l) = max(l,0) + log1p(exp(-|l|))
                    acc += fmaxf(l, 0.f) + log1pf(expf(-fabsf(l))) - l * y;
                }
                tile[lc][r] = 1.f / (1.f + expf(-l));
            }
        }
        __syncthreads();
        if (rows > 0) {
            if ((rows & 3) == 0) {
                const int r4 = rows >> 2;
                const int tot = 64 * r4;
                for (int t = tid; t < tot; t += 256) {
                    const int row = t / r4;
                    const int q = t - row * r4;
                    const int c2 = c0 + row;
                    if (c2 < C) {
                        float4 v;
                        v.x = tile[row][q * 4 + 0];
                        v.y = tile[row][q * 4 + 1];
                        v.z = tile[row][q * 4 + 2];
                        v.w = tile[row][q * 4 + 3];
                        *(float4*)(pT + (size_t)c2 * B + b0 + q * 4) = v;
                    }
                }
            } else {
                const int tot = 64 * rows;
                for (int t = tid; t < tot; t += 256) {
                    const int row = t / rows;
                    const int r = t - row * rows;
                    const int c2 = c0 + row;
                    if (c2 < C) pT[(size_t)c2 * B + b0 + r] = tile[row][r];
                }
            }
        }
        sred[tid] = acc;
        __syncthreads();
        for (int s = 128; s > 0; s >>= 1) {
            if (tid < s) sred[tid] += sred[tid + s];
            __syncthreads();
        }
        if (tid == 0) bce_part[bid] = sred[0];
        return;
    }

    // ---------------- dag scan & compact (segmented, all-nt) ---------------
    const int lsb = bid - nbA;          // local scan block index [0, sbN)
    const int sb  = sb_base + lsb;      // global segment index
    if (tid == 0) lcnt = 0;
    __syncthreads();
    unsigned* __restrict__ seg = elist + (size_t)sb * (size_t)segw;

    const int N  = C * C;
    const int N4 = N >> 2;
    const int NT = N4 / TILEN;
    const int span = (te > tb) ? ((te - tb) + sbN - 1) / sbN : 0;
    const int t0 = tb + lsb * span;
    const int t1 = (t0 + span < te) ? (t0 + span) : te;

    if (t0 < t1) {
        const float* p = dag + ((size_t)t0 * TILEN + tid) * 4;
        f4v a[SCAN_U], b[SCAN_U];
#pragma unroll
        for (int u = 0; u < SCAN_U; ++u) a[u] = ld4nt(p + u * 1024);
        for (int t = t0; t < t1; ++t) {
            const bool last = (t + 1 == t1);
            if (!last) {
#pragma unroll
                for (int u = 0; u < SCAN_U; ++u)
                    b[u] = ld4nt(p + TILEN * 4 + u * 1024);
            }
            PROCESS_TILE(a, t * TILEN);
            if (!last) {
#pragma unroll
                for (int u = 0; u < SCAN_U; ++u) a[u] = b[u];
            }
            p += TILEN * 4;
        }
    }

    if (do_tails) {
        // float4 tail (N4 % TILEN)
        for (int q = NT * TILEN + lsb * 256 + tid; q < N4; q += sbN * 256) {
            f4v d = ld4nt(dag + (size_t)q * 4);
#pragma unroll
            for (int k = 0; k < 4; ++k) {
                if (d[k] > 0.f) {
                    const unsigned e = (unsigned)(q * 4 + k);
                    PUSH_EDGE(e);
                }
            }
        }
        // scalar tail (N % 4)
        for (int e = (N4 << 2) + lsb * 256 + tid; e < N; e += sbN * 256) {
            if (dag[e] > 0.f) PUSH_EDGE((unsigned)e);
        }
    }

    __syncthreads();
    const int n  = lcnt;
    const int nl = (n < LBUF_CAP) ? n : LBUF_CAP;
    for (int t = tid; t < nl; t += 256)
        if (t < segw) seg[t] = lbuf[t];
    if (tid == 0) bcount[sb] = (n < segw) ? n : segw;
}

// ---- Edge processing: one block per segment, wave per edge, lane = batch ---
__global__ void __launch_bounds__(256) k_edges(
        const float* __restrict__ pT,
        const unsigned* __restrict__ elist,
        const int* __restrict__ bcount, int segw, int nseg,
        float* __restrict__ per_term,
        float* __restrict__ npar,
        int B, int C) {
    const int lane = threadIdx.x & 63;
    const int w    = threadIdx.x >> 6;  // wave in block, 0..3
    for (int sb = blockIdx.x; sb < nseg; sb += gridDim.x) {
        int n = bcount[sb];
        if (n > segw) n = segw;
        const unsigned* seg = elist + (size_t)sb * (size_t)segw;
        for (int t = w; t < n; t += 4) {
            const unsigned e = seg[t];
            const unsigned ui = e / (unsigned)C;
            const int i = (int)ui;
            const int j = (int)(e - ui * (unsigned)C);
            const float* pi = pT + (size_t)i * B;
            const float* pj = pT + (size_t)j * B;
            float s = 0.f;
            for (int b = lane; b < B; b += 64) {
                float df = fmaxf(pi[b] - pj[b], 0.f);
                s += df * df;
            }
#pragma unroll
            for (int off = 32; off > 0; off >>= 1) s += __shfl_down(s, off, 64);
            if (lane == 0) {
                atomicAdd(&per_term[i], s);
                atomicAdd(&npar[i], 1.f);
            }
        }
    }
}

// ---- Final scalar reduction ------------------------------------------------
__global__ void k_final(const float* __restrict__ per_term,
                        const float* __restrict__ npar,
                        const float* __restrict__ bce_part, int nb,
                        float* __restrict__ out, int B, int C) {
    float bs = 0.f, ps = 0.f, es = 0.f;
    for (int k = threadIdx.x; k < nb; k += blockDim.x) bs += bce_part[k];
    for (int i = threadIdx.x; i < C; i += blockDim.x) {
        float np = npar[i];
        es += np;
        if (np > 0.f) ps += per_term[i] / ((float)B * np);
    }
    __shared__ float s1[256], s2[256], s3[256];
    s1[threadIdx.x] = bs;
    s2[threadIdx.x] = ps;
    s3[threadIdx.x] = es;
    __syncthreads();
    for (int s = blockDim.x >> 1; s > 0; s >>= 1) {
        if (threadIdx.x < s) {
            s1[threadIdx.x] += s1[threadIdx.x + s];
            s2[threadIdx.x] += s2[threadIdx.x + s];
            s3[threadIdx.x] += s3[threadIdx.x + s];
        }
        __syncthreads();
    }
    if (threadIdx.x == 0) {
        float penalty = (s3[0] > 0.f) ? (s2[0] / s3[0]) : 0.f;
        out[0] = s1[0] / (float)(B * C) + LAMBDA_DAG * penalty;
    }
}

extern "C" void kernel_launch(void* const* d_in, const int* in_sizes, int n_in,
                              void* d_out, int out_size, void* d_ws, size_t ws_size,
                              hipStream_t stream) {
    const float* logits = (const float*)d_in[0];
    const float* labels = (const float*)d_in[1];
    const float* dag    = (const float*)d_in[2];
    float* out = (float*)d_out;

    const int C = (int)(sqrt((double)in_sizes[2]) + 0.5);
    const int B = in_sizes[0] / C;

    const int gridAx = (C + 63) / 64;
    const int gridAy = (B + 15) / 16;
    const int nbA = gridAx * gridAy;

    const int N4 = (C * C) >> 2;
    const int NT = N4 / TILEN;                     // 3051 full tiles at C=5000
    const int scanB = 2048;                        // R6-proven parallelism
    const int nseg = scanB;
    const int span = (NT > 0) ? (NT + scanB - 1) / scanB : 0;
    const long long segw_full = (long long)(span + 1) * TILEN * 4;

    float* ws       = (float*)d_ws;
    float* pT       = ws;                          // C*B
    float* per_term = pT + (size_t)C * B;          // C
    float* nparw    = per_term + C;                // C
    float* bce_part = nparw + C;                   // nbA
    int*   bcount   = (int*)(bce_part + nbA);      // nseg
    unsigned* elist = (unsigned*)(bcount + nseg);  // nseg * segw

    const size_t base_words = (size_t)C * B + 2 * (size_t)C + nbA + nseg;
    const size_t ws_words = ws_size / 4;
    long long avail = (ws_words > base_words)
                    ? (long long)(ws_words - base_words) : 0;

    int fused, inline_ok, segw;
    if (avail >= segw_full * nseg) {
        fused = 1; inline_ok = 0;
        segw = (int)segw_full;
    } else {
        fused = 0; inline_ok = 1;                  // probs first, inline overflow
        long long sw = avail / nseg;
        if (sw > 0x7fffffffLL) sw = 0x7fffffffLL;
        segw = (int)(sw < 0 ? 0 : sw);
    }

    if (fused) {
        // Single fused launch: probs blocks + all-nt scan of every tile + tails
        k_main<<<nbA + scanB, 256, 0, stream>>>(
            logits, labels, dag, pT, bce_part, per_term, nparw,
            elist, bcount, segw, 0,
            0, NT, 0, scanB, 1, gridAx, gridAy, B, C);
    } else {
        k_main<<<nbA, 256, 0, stream>>>(           // probs only
            logits, labels, dag, pT, bce_part, per_term, nparw,
            elist, bcount, segw, 0,
            0, 0, 0, 1, 0, gridAx, gridAy, B, C);
        k_main<<<scanB, 256, 0, stream>>>(         // scan with inline overflow
            logits, labels, dag, pT, bce_part, per_term, nparw,
            elist, bcount, segw, inline_ok,
            0, NT, 0, scanB, 1, 0, 0, B, C);
    }

    k_edges<<<nseg, 256, 0, stream>>>(pT, elist, bcount, segw, nseg,
                                      per_term, nparw, B, C);
    k_final<<<1, 256, 0, stream>>>(per_term, nparw, bce_part, nbA, out, B, C);
}